// Round 1
// baseline (1401.609 us; speedup 1.0000x reference)
//
#include <hip/hip_runtime.h>
#include <cstddef>

constexpr int N_ = 65536;
constexpr int K_ = 16;
constexpr int E_ = N_ * K_;      // 1048576
constexpr int C_ = 64;
#define EPS_ 1e-5f

// ---------------------------------------------------------------------------
// BN stats reducer: partials[p][2*nchp] (sums at [c], sumsq at [nchp+c]).
// Writes scale at ss[c], shift at ss[nchp+c].
__global__ void k_reduce_bn(const float* __restrict__ part, int P, int nchp, int nch,
                            float invM, const float* __restrict__ g,
                            const float* __restrict__ b, float* __restrict__ ss)
{
    int c = threadIdx.x;
    if (c >= nch) return;
    double s = 0.0, q = 0.0;
    for (int p = 0; p < P; ++p) {
        s += (double)part[p * 2 * nchp + c];
        q += (double)part[p * 2 * nchp + nchp + c];
    }
    float mean = (float)(s * (double)invM);
    float var  = (float)(q * (double)invM) - mean * mean;
    float sc = g[c] * rsqrtf(var + EPS_);
    ss[c] = sc;
    ss[nchp + c] = b[c] - mean * sc;
}

// ---------------------------------------------------------------------------
// Column stats over [65536 x 64] row-major buffer. Grid 256 blocks x 256 thr.
__global__ __launch_bounds__(256)
void k_colstats(const float* __restrict__ buf, float* __restrict__ part)
{
    int t = threadIdx.x, c = t & 63, rg = t >> 6;
    float s = 0.f, q = 0.f;
    int base = blockIdx.x * 256 + rg * 64;
    for (int i = 0; i < 64; ++i) {
        float v = buf[(size_t)(base + i) * 64 + c];
        s += v; q = fmaf(v, v, q);
    }
    __shared__ float red[2][256];
    red[0][t] = s; red[1][t] = q;
    __syncthreads();
    if (t < 64) {
        float S = red[0][t] + red[0][t + 64] + red[0][t + 128] + red[0][t + 192];
        float Q = red[1][t] + red[1][t + 64] + red[1][t + 128] + red[1][t + 192];
        part[blockIdx.x * 128 + t]      = S;
        part[blockIdx.x * 128 + 64 + t] = Q;
    }
}

// ---------------------------------------------------------------------------
// One 64-wide row GEMM: outrow[c] = bias[c] + sum_k xr[k]*W[c*64+k]
__device__ __forceinline__ void gemm_row(const float xr[64], const float* __restrict__ W,
                                         const float* __restrict__ bias,
                                         float* __restrict__ outrow)
{
    float4* o4 = (float4*)outrow;
    for (int c4 = 0; c4 < 16; ++c4) {
        int cb = 4 * c4;
        float4 acc;
        acc.x = bias ? bias[cb + 0] : 0.f;
        acc.y = bias ? bias[cb + 1] : 0.f;
        acc.z = bias ? bias[cb + 2] : 0.f;
        acc.w = bias ? bias[cb + 3] : 0.f;
#pragma unroll
        for (int k = 0; k < 64; ++k) {
            float xv = xr[k];
            acc.x = fmaf(xv, W[(cb + 0) * 64 + k], acc.x);
            acc.y = fmaf(xv, W[(cb + 1) * 64 + k], acc.y);
            acc.z = fmaf(xv, W[(cb + 2) * 64 + k], acc.z);
            acc.w = fmaf(xv, W[(cb + 3) * 64 + k], acc.w);
        }
        o4[c4] = acc;
    }
}

// y = (optional relu(bn(in))) @ W^T (+bias). One thread per node row.
__global__ __launch_bounds__(256)
void k_gemm_node(const float* __restrict__ in, const float* __restrict__ W,
                 const float* __restrict__ bias, const float* __restrict__ ss,
                 float* __restrict__ out)
{
    int n = blockIdx.x * 256 + threadIdx.x;
    float xr[64];
    const float4* inr = (const float4*)(in + (size_t)n * 64);
#pragma unroll
    for (int i = 0; i < 16; ++i) {
        float4 v = inr[i];
        xr[4 * i + 0] = v.x; xr[4 * i + 1] = v.y;
        xr[4 * i + 2] = v.z; xr[4 * i + 3] = v.w;
    }
    if (ss) {
#pragma unroll
        for (int k = 0; k < 64; ++k)
            xr[k] = fmaxf(fmaf(xr[k], ss[k], ss[64 + k]), 0.f);
    }
    gemm_row(xr, W, bias, out + (size_t)n * 64);
}

// h = relu(bn1(y)); a_src = h@Wa^T+ba; a_dst = h@Wb^T+bb; hW = h@Wc^T+bc
__global__ __launch_bounds__(256)
void k_gemm3(const float* __restrict__ y, const float* __restrict__ ss,
             const float* __restrict__ Wa, const float* __restrict__ ba,
             const float* __restrict__ Wb, const float* __restrict__ bb,
             const float* __restrict__ Wc, const float* __restrict__ bc,
             float* __restrict__ oa, float* __restrict__ ob, float* __restrict__ oc)
{
    int n = blockIdx.x * 256 + threadIdx.x;
    float xr[64];
    const float4* inr = (const float4*)(y + (size_t)n * 64);
#pragma unroll
    for (int i = 0; i < 16; ++i) {
        float4 v = inr[i];
        xr[4 * i + 0] = v.x; xr[4 * i + 1] = v.y;
        xr[4 * i + 2] = v.z; xr[4 * i + 3] = v.w;
    }
#pragma unroll
    for (int k = 0; k < 64; ++k)
        xr[k] = fmaxf(fmaf(xr[k], ss[k], ss[64 + k]), 0.f);
    gemm_row(xr, Wa, ba, oa + (size_t)n * 64);
    gemm_row(xr, Wb, bb, ob + (size_t)n * 64);
    gemm_row(xr, Wc, bc, oc + (size_t)n * 64);
}

// ---------------------------------------------------------------------------
// d-vector (pos_nn hidden after BN+ReLU) for one edge. All weights uniform.
__device__ __forceinline__ void compute_d(const float* __restrict__ pos, int si, int di,
                                          const float* __restrict__ pw1,
                                          const float* __restrict__ pb1,
                                          const float* __restrict__ sspos,
                                          float& d0, float& d1, float& d2)
{
    float rx = pos[3 * si + 0] - pos[3 * di + 0];
    float ry = pos[3 * si + 1] - pos[3 * di + 1];
    float rz = pos[3 * si + 2] - pos[3 * di + 2];
    float u0 = fmaf(rx, pw1[0], fmaf(ry, pw1[1], fmaf(rz, pw1[2], pb1[0])));
    float u1 = fmaf(rx, pw1[3], fmaf(ry, pw1[4], fmaf(rz, pw1[5], pb1[1])));
    float u2 = fmaf(rx, pw1[6], fmaf(ry, pw1[7], fmaf(rz, pw1[8], pb1[2])));
    d0 = fmaxf(fmaf(u0, sspos[0], sspos[4]), 0.f);
    d1 = fmaxf(fmaf(u1, sspos[1], sspos[5]), 0.f);
    d2 = fmaxf(fmaf(u2, sspos[2], sspos[6]), 0.f);
}

// ---------------------------------------------------------------------------
// Stats of u = rel @ pos_w1^T + pos_b1 over E edges (3 channels, pad 4).
__global__ __launch_bounds__(256)
void k_pos_stats(const float* __restrict__ pos, const int* __restrict__ src,
                 const float* __restrict__ pw1, const float* __restrict__ pb1,
                 float* __restrict__ part)
{
    float s0 = 0, s1 = 0, s2 = 0, q0 = 0, q1 = 0, q2 = 0;
    int tid = blockIdx.x * 256 + threadIdx.x;
    for (int e = tid; e < E_; e += 1024 * 256) {
        int si = src[e], di = e >> 4;
        float rx = pos[3 * si + 0] - pos[3 * di + 0];
        float ry = pos[3 * si + 1] - pos[3 * di + 1];
        float rz = pos[3 * si + 2] - pos[3 * di + 2];
        float u0 = fmaf(rx, pw1[0], fmaf(ry, pw1[1], fmaf(rz, pw1[2], pb1[0])));
        float u1 = fmaf(rx, pw1[3], fmaf(ry, pw1[4], fmaf(rz, pw1[5], pb1[1])));
        float u2 = fmaf(rx, pw1[6], fmaf(ry, pw1[7], fmaf(rz, pw1[8], pb1[2])));
        s0 += u0; q0 = fmaf(u0, u0, q0);
        s1 += u1; q1 = fmaf(u1, u1, q1);
        s2 += u2; q2 = fmaf(u2, u2, q2);
    }
#pragma unroll
    for (int m = 1; m < 64; m <<= 1) {
        s0 += __shfl_xor(s0, m, 64); s1 += __shfl_xor(s1, m, 64); s2 += __shfl_xor(s2, m, 64);
        q0 += __shfl_xor(q0, m, 64); q1 += __shfl_xor(q1, m, 64); q2 += __shfl_xor(q2, m, 64);
    }
    __shared__ float red[4][8];
    int wv = threadIdx.x >> 6, ln = threadIdx.x & 63;
    if (ln == 0) {
        red[wv][0] = s0; red[wv][1] = s1; red[wv][2] = s2; red[wv][3] = 0.f;
        red[wv][4] = q0; red[wv][5] = q1; red[wv][6] = q2; red[wv][7] = 0.f;
    }
    __syncthreads();
    if (threadIdx.x < 8)
        part[blockIdx.x * 8 + threadIdx.x] =
            red[0][threadIdx.x] + red[1][threadIdx.x] + red[2][threadIdx.x] + red[3][threadIdx.x];
}

// ---------------------------------------------------------------------------
// Stats of a = a_src[src] - a_dst[dst] + delta over E edges (64 channels).
// One thread per edge; a recomputed, never stored.
__global__ __launch_bounds__(256)
void k_abn1_stats(const float* __restrict__ pos, const int* __restrict__ src,
                  const float* __restrict__ asrc, const float* __restrict__ adst,
                  const float* __restrict__ pw1, const float* __restrict__ pb1,
                  const float* __restrict__ sspos, const float* __restrict__ pw2,
                  const float* __restrict__ pb2, float* __restrict__ part)
{
    float sacc[64], qacc[64];
#pragma unroll
    for (int i = 0; i < 64; ++i) { sacc[i] = 0.f; qacc[i] = 0.f; }
    int tid = blockIdx.x * 256 + threadIdx.x;
    for (int e = tid; e < E_; e += 1024 * 256) {
        int si = src[e], di = e >> 4;
        float d0, d1, d2;
        compute_d(pos, si, di, pw1, pb1, sspos, d0, d1, d2);
        const float4* ar = (const float4*)(asrc + (size_t)si * 64);
        const float4* dr = (const float4*)(adst + (size_t)di * 64);
#pragma unroll
        for (int c4 = 0; c4 < 16; ++c4) {
            float4 av = ar[c4], dv = dr[c4];
            int c = 4 * c4;
#define PROCA(comp, cc) { \
            float del = fmaf(d0, pw2[3*(cc)+0], fmaf(d1, pw2[3*(cc)+1], fmaf(d2, pw2[3*(cc)+2], pb2[(cc)]))); \
            float a = av.comp - dv.comp + del; \
            sacc[(cc)] += a; qacc[(cc)] = fmaf(a, a, qacc[(cc)]); }
            PROCA(x, c + 0) PROCA(y, c + 1) PROCA(z, c + 2) PROCA(w, c + 3)
#undef PROCA
        }
    }
#pragma unroll
    for (int c = 0; c < 64; ++c) {
        float s = sacc[c], q = qacc[c];
#pragma unroll
        for (int m = 1; m < 64; m <<= 1) { s += __shfl_xor(s, m, 64); q += __shfl_xor(q, m, 64); }
        sacc[c] = s; qacc[c] = q;
    }
    __shared__ float red[4][128];
    int wv = threadIdx.x >> 6, ln = threadIdx.x & 63;
    if (ln == 0) {
#pragma unroll
        for (int c = 0; c < 64; ++c) { red[wv][c] = sacc[c]; red[wv][64 + c] = qacc[c]; }
    }
    __syncthreads();
    if (threadIdx.x < 128)
        part[blockIdx.x * 128 + threadIdx.x] =
            red[0][threadIdx.x] + red[1][threadIdx.x] + red[2][threadIdx.x] + red[3][threadIdx.x];
}

// ---------------------------------------------------------------------------
// t1 = relu(abn1(a)) @ attn_w1^T + attn_b1  [E,8]; also abn2 stats (8 ch).
__global__ __launch_bounds__(256)
void k_edge_t1(const float* __restrict__ pos, const int* __restrict__ src,
               const float* __restrict__ asrc, const float* __restrict__ adst,
               const float* __restrict__ pw1, const float* __restrict__ pb1,
               const float* __restrict__ sspos, const float* __restrict__ pw2,
               const float* __restrict__ pb2, const float* __restrict__ ssa1,
               const float* __restrict__ aw1, const float* __restrict__ ab1,
               float* __restrict__ t1, float* __restrict__ part)
{
    float ssum[8], sq[8];
#pragma unroll
    for (int j = 0; j < 8; ++j) { ssum[j] = 0.f; sq[j] = 0.f; }
    int tid = blockIdx.x * 256 + threadIdx.x;
    for (int e = tid; e < E_; e += 1024 * 256) {
        int si = src[e], di = e >> 4;
        float d0, d1, d2;
        compute_d(pos, si, di, pw1, pb1, sspos, d0, d1, d2);
        const float4* ar = (const float4*)(asrc + (size_t)si * 64);
        const float4* dr = (const float4*)(adst + (size_t)di * 64);
        float tp[8];
#pragma unroll
        for (int j = 0; j < 8; ++j) tp[j] = ab1[j];
#pragma unroll
        for (int c4 = 0; c4 < 16; ++c4) {
            float4 av = ar[c4], dv = dr[c4];
            int c = 4 * c4;
#define PROCB(comp, cc) { \
            float del = fmaf(d0, pw2[3*(cc)+0], fmaf(d1, pw2[3*(cc)+1], fmaf(d2, pw2[3*(cc)+2], pb2[(cc)]))); \
            float a = av.comp - dv.comp + del; \
            float an = fmaxf(fmaf(a, ssa1[(cc)], ssa1[64 + (cc)]), 0.f); \
            _Pragma("unroll") \
            for (int j = 0; j < 8; ++j) tp[j] = fmaf(an, aw1[j * 64 + (cc)], tp[j]); }
            PROCB(x, c + 0) PROCB(y, c + 1) PROCB(z, c + 2) PROCB(w, c + 3)
#undef PROCB
        }
        float4 o0 = {tp[0], tp[1], tp[2], tp[3]};
        float4 o1 = {tp[4], tp[5], tp[6], tp[7]};
        float4* t4 = (float4*)(t1 + (size_t)e * 8);
        t4[0] = o0; t4[1] = o1;
#pragma unroll
        for (int j = 0; j < 8; ++j) { ssum[j] += tp[j]; sq[j] = fmaf(tp[j], tp[j], sq[j]); }
    }
#pragma unroll
    for (int j = 0; j < 8; ++j) {
        float s = ssum[j], q = sq[j];
#pragma unroll
        for (int m = 1; m < 64; m <<= 1) { s += __shfl_xor(s, m, 64); q += __shfl_xor(q, m, 64); }
        ssum[j] = s; sq[j] = q;
    }
    __shared__ float red[4][16];
    int wv = threadIdx.x >> 6, ln = threadIdx.x & 63;
    if (ln == 0) {
#pragma unroll
        for (int j = 0; j < 8; ++j) { red[wv][j] = ssum[j]; red[wv][8 + j] = sq[j]; }
    }
    __syncthreads();
    if (threadIdx.x < 16)
        part[blockIdx.x * 16 + threadIdx.x] =
            red[0][threadIdx.x] + red[1][threadIdx.x] + red[2][threadIdx.x] + red[3][threadIdx.x];
}

// ---------------------------------------------------------------------------
// Final edge pass: t2 = relu(abn2(t1)) @ attn_w2^T + attn_b2; softmax over
// each node's 16 contiguous edges (16-lane shfl groups); weighted aggregate
// out[n,c] = sum_k alpha[k][c&7] * (hW[src_k,c] + delta_k[c]).
__global__ __launch_bounds__(256)
void k_node_aggr(const float* __restrict__ pos, const int* __restrict__ src,
                 const float* __restrict__ t1, const float* __restrict__ ssa2,
                 const float* __restrict__ aw2, const float* __restrict__ ab2,
                 const float* __restrict__ hw, const float* __restrict__ sspos,
                 const float* __restrict__ pw1, const float* __restrict__ pb1,
                 const float* __restrict__ pw2, const float* __restrict__ pb2,
                 float* __restrict__ out)
{
    int t = threadIdx.x;
    int e = blockIdx.x * 256 + t;
    int n = e >> 4;
    int k = t & 15;
    const float4* t4 = (const float4*)(t1 + (size_t)e * 8);
    float4 ta = t4[0], tb = t4[1];
    float tv[8] = {ta.x, ta.y, ta.z, ta.w, tb.x, tb.y, tb.z, tb.w};
    float tn[8];
#pragma unroll
    for (int j = 0; j < 8; ++j) tn[j] = fmaxf(fmaf(tv[j], ssa2[j], ssa2[8 + j]), 0.f);
    float al[8];
#pragma unroll
    for (int j = 0; j < 8; ++j) {
        float acc = ab2[j];
#pragma unroll
        for (int i = 0; i < 8; ++i) acc = fmaf(tn[i], aw2[j * 8 + i], acc);
        float m = acc;
#pragma unroll
        for (int msk = 1; msk < 16; msk <<= 1) m = fmaxf(m, __shfl_xor(m, msk, 64));
        float ex = __expf(acc - m);
        float sm = ex;
#pragma unroll
        for (int msk = 1; msk < 16; msk <<= 1) sm += __shfl_xor(sm, msk, 64);
        al[j] = ex / sm;
    }
    int si = src[e];
    float d0, d1, d2;
    compute_d(pos, si, n, pw1, pb1, sspos, d0, d1, d2);
    const float4* hr = (const float4*)(hw + (size_t)si * 64);
    float4 keep = {0.f, 0.f, 0.f, 0.f};
#pragma unroll
    for (int c4 = 0; c4 < 16; ++c4) {
        float4 hv = hr[c4];
        int c = 4 * c4;
        float m0 = (hv.x + fmaf(d0, pw2[3*c+0], fmaf(d1, pw2[3*c+1],  fmaf(d2, pw2[3*c+2],  pb2[c+0])))) * al[(c+0)&7];
        float m1 = (hv.y + fmaf(d0, pw2[3*c+3], fmaf(d1, pw2[3*c+4],  fmaf(d2, pw2[3*c+5],  pb2[c+1])))) * al[(c+1)&7];
        float m2 = (hv.z + fmaf(d0, pw2[3*c+6], fmaf(d1, pw2[3*c+7],  fmaf(d2, pw2[3*c+8],  pb2[c+2])))) * al[(c+2)&7];
        float m3 = (hv.w + fmaf(d0, pw2[3*c+9], fmaf(d1, pw2[3*c+10], fmaf(d2, pw2[3*c+11], pb2[c+3])))) * al[(c+3)&7];
#pragma unroll
        for (int msk = 1; msk < 16; msk <<= 1) {
            m0 += __shfl_xor(m0, msk, 64); m1 += __shfl_xor(m1, msk, 64);
            m2 += __shfl_xor(m2, msk, 64); m3 += __shfl_xor(m3, msk, 64);
        }
        if (k == c4) { keep.x = m0; keep.y = m1; keep.z = m2; keep.w = m3; }
    }
    ((float4*)out)[(size_t)n * 16 + k] = keep;
}

// ---------------------------------------------------------------------------
// out = relu(bn3(y3) + x_skip)
__global__ __launch_bounds__(256)
void k_final(const float* __restrict__ y3, const float* __restrict__ ss3,
             const float* __restrict__ x, float* __restrict__ out)
{
    int i = blockIdx.x * 256 + threadIdx.x;   // float4 index
    int c4 = i & 15;
    float4 sc = ((const float4*)ss3)[c4];
    float4 sh = ((const float4*)(ss3 + 64))[c4];
    float4 v  = ((const float4*)y3)[i];
    float4 xs = ((const float4*)x)[i];
    float4 o;
    o.x = fmaxf(fmaf(v.x, sc.x, sh.x) + xs.x, 0.f);
    o.y = fmaxf(fmaf(v.y, sc.y, sh.y) + xs.y, 0.f);
    o.z = fmaxf(fmaf(v.z, sc.z, sh.z) + xs.z, 0.f);
    o.w = fmaxf(fmaf(v.w, sc.w, sh.w) + xs.w, 0.f);
    ((float4*)out)[i] = o;
}

// ---------------------------------------------------------------------------
extern "C" void kernel_launch(void* const* d_in, const int* in_sizes, int n_in,
                              void* d_out, int out_size, void* d_ws, size_t ws_size,
                              hipStream_t stream)
{
    const float* x    = (const float*)d_in[0];
    const float* pos  = (const float*)d_in[1];
    const int*   src  = (const int*)d_in[2];           // edge_index row 0
    const float* W_in = (const float*)d_in[3];
    const float* W_out= (const float*)d_in[4];
    const float* pw1  = (const float*)d_in[5];
    const float* pb1  = (const float*)d_in[6];
    const float* pbg  = (const float*)d_in[7];
    const float* pbb  = (const float*)d_in[8];
    const float* pw2  = (const float*)d_in[9];
    const float* pb2  = (const float*)d_in[10];
    const float* a1g  = (const float*)d_in[11];
    const float* a1b  = (const float*)d_in[12];
    const float* aw1  = (const float*)d_in[13];
    const float* ab1  = (const float*)d_in[14];
    const float* a2g  = (const float*)d_in[15];
    const float* a2b  = (const float*)d_in[16];
    const float* aw2  = (const float*)d_in[17];
    const float* ab2  = (const float*)d_in[18];
    const float* linw = (const float*)d_in[19];
    const float* linb = (const float*)d_in[20];
    const float* srcw = (const float*)d_in[21];
    const float* srcb = (const float*)d_in[22];
    const float* dstw = (const float*)d_in[23];
    const float* dstb = (const float*)d_in[24];
    const float* bn1g = (const float*)d_in[25];
    const float* bn1b = (const float*)d_in[26];
    const float* bn2g = (const float*)d_in[27];
    const float* bn2b = (const float*)d_in[28];
    const float* bn3g = (const float*)d_in[29];
    const float* bn3b = (const float*)d_in[30];
    float* outp = (float*)d_out;

    float* ws = (float*)d_ws;
    const size_t NC = (size_t)N_ * C_;
    float* buf_y    = ws;                 // y1, later y3
    float* buf_asrc = ws + NC;            // a_src, later reused as `out` aggregate
    float* buf_adst = ws + 2 * NC;
    float* buf_hw   = ws + 3 * NC;
    float* buf_t1   = ws + 4 * NC;        // [E,8]
    float* pbase    = ws + 4 * NC + (size_t)E_ * 8;
    float* p_bn1  = pbase;                 // 256*128
    float* p_pos  = p_bn1  + 256 * 128;    // 1024*8
    float* p_abn1 = p_pos  + 1024 * 8;     // 1024*128
    float* p_abn2 = p_abn1 + 1024 * 128;   // 1024*16
    float* p_bn2  = p_abn2 + 1024 * 16;    // 256*128
    float* p_bn3  = p_bn2  + 256 * 128;    // 256*128
    float* ssb    = p_bn3  + 256 * 128;
    float* ss_bn1 = ssb;         // [scale 64][shift 64]
    float* ss_pos = ssb + 128;   // [scale 4][shift 4]
    float* ss_a1  = ssb + 136;   // 128
    float* ss_a2  = ssb + 264;   // 16
    float* ss_bn2 = ssb + 280;   // 128
    float* ss_bn3 = ssb + 408;   // 128

    float* buf_out = buf_asrc;   // reuse after a_src consumed

    // 1) y1 = x @ W_in^T
    k_gemm_node<<<256, 256, 0, stream>>>(x, W_in, nullptr, nullptr, buf_y);
    // 2-3) bn1 stats
    k_colstats<<<256, 256, 0, stream>>>(buf_y, p_bn1);
    k_reduce_bn<<<1, 64, 0, stream>>>(p_bn1, 256, 64, 64, 1.f / N_, bn1g, bn1b, ss_bn1);
    // 4) h = relu(bn1(y1)); a_src/a_dst/hW
    k_gemm3<<<256, 256, 0, stream>>>(buf_y, ss_bn1, srcw, srcb, dstw, dstb, linw, linb,
                                     buf_asrc, buf_adst, buf_hw);
    // 5-6) pos-BN stats
    k_pos_stats<<<1024, 256, 0, stream>>>(pos, src, pw1, pb1, p_pos);
    k_reduce_bn<<<1, 64, 0, stream>>>(p_pos, 1024, 4, 3, 1.f / E_, pbg, pbb, ss_pos);
    // 7-8) attn_bn1 stats (a recomputed on the fly)
    k_abn1_stats<<<1024, 256, 0, stream>>>(pos, src, buf_asrc, buf_adst,
                                           pw1, pb1, ss_pos, pw2, pb2, p_abn1);
    k_reduce_bn<<<1, 64, 0, stream>>>(p_abn1, 1024, 64, 64, 1.f / E_, a1g, a1b, ss_a1);
    // 9-10) t1 = relu(abn1(a)) @ attn_w1^T + b1 ; abn2 stats
    k_edge_t1<<<1024, 256, 0, stream>>>(pos, src, buf_asrc, buf_adst,
                                        pw1, pb1, ss_pos, pw2, pb2,
                                        ss_a1, aw1, ab1, buf_t1, p_abn2);
    k_reduce_bn<<<1, 64, 0, stream>>>(p_abn2, 1024, 8, 8, 1.f / E_, a2g, a2b, ss_a2);
    // 11) softmax + weighted aggregate -> out [N,64]
    k_node_aggr<<<E_ / 256, 256, 0, stream>>>(pos, src, buf_t1, ss_a2, aw2, ab2,
                                              buf_hw, ss_pos, pw1, pb1, pw2, pb2, buf_out);
    // 12-13) bn2 stats
    k_colstats<<<256, 256, 0, stream>>>(buf_out, p_bn2);
    k_reduce_bn<<<1, 64, 0, stream>>>(p_bn2, 256, 64, 64, 1.f / N_, bn2g, bn2b, ss_bn2);
    // 14) y3 = relu(bn2(out)) @ W_out^T
    k_gemm_node<<<256, 256, 0, stream>>>(buf_out, W_out, nullptr, ss_bn2, buf_y);
    // 15-16) bn3 stats
    k_colstats<<<256, 256, 0, stream>>>(buf_y, p_bn3);
    k_reduce_bn<<<1, 64, 0, stream>>>(p_bn3, 256, 64, 64, 1.f / N_, bn3g, bn3b, ss_bn3);
    // 17) out = relu(bn3(y3) + x)
    k_final<<<(N_ * C_ / 4) / 256, 256, 0, stream>>>(buf_y, ss_bn3, x, outp);

    (void)in_sizes; (void)n_in; (void)out_size; (void)ws_size;
}

// Round 3
// 667.594 us; speedup vs baseline: 2.0995x; 2.0995x over previous
//
#include <hip/hip_runtime.h>
#include <cstddef>

constexpr int N_ = 65536;
constexpr int K_ = 16;
constexpr int E_ = N_ * K_;      // 1048576
constexpr int C_ = 64;
#define EPS_ 1e-5f

// ---------------------------------------------------------------------------
// BN stats reducer: partials[p][2*nchp] (sums at [c], sumsq at [nchp+c]).
// Writes scale at ss[c], shift at ss[nchp+c].
// R1 post-mortem: the old 64-thread serial version was latency-bound at
// ~620 cyc/iteration (remote-L2/L3 loads, no pipelining) = 265 us/dispatch.
// Now: 1024 threads, R=1024/nchp rows per channel, 4x unroll (8 loads in
// flight), LDS tree. Expected <5 us.
__global__ __launch_bounds__(1024)
void k_reduce_bn(const float* __restrict__ part, int P, int nchp, int nch,
                 float invM, const float* __restrict__ g,
                 const float* __restrict__ b, float* __restrict__ ss)
{
    int t = threadIdx.x;
    int c = t & (nchp - 1);
    int r = t / nchp;             // 0..R-1
    int R = 1024 / nchp;
    int stride = 2 * nchp;
    float s0 = 0.f, s1 = 0.f, s2 = 0.f, s3 = 0.f;
    float q0 = 0.f, q1 = 0.f, q2 = 0.f, q3 = 0.f;
    int p = r;
    for (; p + 3 * R < P; p += 4 * R) {
        int i0 = p * stride + c;
        int i1 = (p + R) * stride + c;
        int i2 = (p + 2 * R) * stride + c;
        int i3 = (p + 3 * R) * stride + c;
        s0 += part[i0];        s1 += part[i1];
        s2 += part[i2];        s3 += part[i3];
        q0 += part[i0 + nchp]; q1 += part[i1 + nchp];
        q2 += part[i2 + nchp]; q3 += part[i3 + nchp];
    }
    for (; p < P; p += R) {
        s0 += part[p * stride + c];
        q0 += part[p * stride + nchp + c];
    }
    float s = (s0 + s1) + (s2 + s3);
    float q = (q0 + q1) + (q2 + q3);
    __shared__ float reds[1024], redq[1024];
    reds[t] = s; redq[t] = q;
    __syncthreads();
    for (int off = 512; off >= nchp; off >>= 1) {
        if (t < off) { reds[t] += reds[t + off]; redq[t] += redq[t + off]; }
        __syncthreads();
    }
    if (t < nch) {
        float mean = reds[t] * invM;
        float var  = fmaxf(redq[t] * invM - mean * mean, 0.f);
        float sc = g[t] * rsqrtf(var + EPS_);
        ss[t] = sc;
        ss[nchp + t] = b[t] - mean * sc;
    }
}

// ---------------------------------------------------------------------------
// Column stats over [65536 x 64] row-major buffer. Grid 256 blocks x 256 thr.
__global__ __launch_bounds__(256)
void k_colstats(const float* __restrict__ buf, float* __restrict__ part)
{
    int t = threadIdx.x, c = t & 63, rg = t >> 6;
    float s = 0.f, q = 0.f;
    int base = blockIdx.x * 256 + rg * 64;
    for (int i = 0; i < 64; ++i) {
        float v = buf[(size_t)(base + i) * 64 + c];
        s += v; q = fmaf(v, v, q);
    }
    __shared__ float red[2][256];
    red[0][t] = s; red[1][t] = q;
    __syncthreads();
    if (t < 64) {
        float S = red[0][t] + red[0][t + 64] + red[0][t + 128] + red[0][t + 192];
        float Q = red[1][t] + red[1][t + 64] + red[1][t + 128] + red[1][t + 192];
        part[blockIdx.x * 128 + t]      = S;
        part[blockIdx.x * 128 + 64 + t] = Q;
    }
}

// ---------------------------------------------------------------------------
// One 64-wide row GEMM: outrow[c] = bias[c] + sum_k xr[k]*W[c*64+k]
__device__ __forceinline__ void gemm_row(const float xr[64], const float* __restrict__ W,
                                         const float* __restrict__ bias,
                                         float* __restrict__ outrow)
{
    float4* o4 = (float4*)outrow;
    for (int c4 = 0; c4 < 16; ++c4) {
        int cb = 4 * c4;
        float4 acc;
        acc.x = bias ? bias[cb + 0] : 0.f;
        acc.y = bias ? bias[cb + 1] : 0.f;
        acc.z = bias ? bias[cb + 2] : 0.f;
        acc.w = bias ? bias[cb + 3] : 0.f;
#pragma unroll
        for (int k = 0; k < 64; ++k) {
            float xv = xr[k];
            acc.x = fmaf(xv, W[(cb + 0) * 64 + k], acc.x);
            acc.y = fmaf(xv, W[(cb + 1) * 64 + k], acc.y);
            acc.z = fmaf(xv, W[(cb + 2) * 64 + k], acc.z);
            acc.w = fmaf(xv, W[(cb + 3) * 64 + k], acc.w);
        }
        o4[c4] = acc;
    }
}

// y = (optional relu(bn(in))) @ W^T (+bias). One thread per node row.
__global__ __launch_bounds__(256)
void k_gemm_node(const float* __restrict__ in, const float* __restrict__ W,
                 const float* __restrict__ bias, const float* __restrict__ ss,
                 float* __restrict__ out)
{
    int n = blockIdx.x * 256 + threadIdx.x;
    float xr[64];
    const float4* inr = (const float4*)(in + (size_t)n * 64);
#pragma unroll
    for (int i = 0; i < 16; ++i) {
        float4 v = inr[i];
        xr[4 * i + 0] = v.x; xr[4 * i + 1] = v.y;
        xr[4 * i + 2] = v.z; xr[4 * i + 3] = v.w;
    }
    if (ss) {
#pragma unroll
        for (int k = 0; k < 64; ++k)
            xr[k] = fmaxf(fmaf(xr[k], ss[k], ss[64 + k]), 0.f);
    }
    gemm_row(xr, W, bias, out + (size_t)n * 64);
}

// h = relu(bn1(y)); a_src = h@Wa^T+ba; a_dst = h@Wb^T+bb; hW = h@Wc^T+bc
__global__ __launch_bounds__(256)
void k_gemm3(const float* __restrict__ y, const float* __restrict__ ss,
             const float* __restrict__ Wa, const float* __restrict__ ba,
             const float* __restrict__ Wb, const float* __restrict__ bb,
             const float* __restrict__ Wc, const float* __restrict__ bc,
             float* __restrict__ oa, float* __restrict__ ob, float* __restrict__ oc)
{
    int n = blockIdx.x * 256 + threadIdx.x;
    float xr[64];
    const float4* inr = (const float4*)(y + (size_t)n * 64);
#pragma unroll
    for (int i = 0; i < 16; ++i) {
        float4 v = inr[i];
        xr[4 * i + 0] = v.x; xr[4 * i + 1] = v.y;
        xr[4 * i + 2] = v.z; xr[4 * i + 3] = v.w;
    }
#pragma unroll
    for (int k = 0; k < 64; ++k)
        xr[k] = fmaxf(fmaf(xr[k], ss[k], ss[64 + k]), 0.f);
    gemm_row(xr, Wa, ba, oa + (size_t)n * 64);
    gemm_row(xr, Wb, bb, ob + (size_t)n * 64);
    gemm_row(xr, Wc, bc, oc + (size_t)n * 64);
}

// ---------------------------------------------------------------------------
// d-vector (pos_nn hidden after BN+ReLU) for one edge. All weights uniform.
__device__ __forceinline__ void compute_d(const float* __restrict__ pos, int si, int di,
                                          const float* __restrict__ pw1,
                                          const float* __restrict__ pb1,
                                          const float* __restrict__ sspos,
                                          float& d0, float& d1, float& d2)
{
    float rx = pos[3 * si + 0] - pos[3 * di + 0];
    float ry = pos[3 * si + 1] - pos[3 * di + 1];
    float rz = pos[3 * si + 2] - pos[3 * di + 2];
    float u0 = fmaf(rx, pw1[0], fmaf(ry, pw1[1], fmaf(rz, pw1[2], pb1[0])));
    float u1 = fmaf(rx, pw1[3], fmaf(ry, pw1[4], fmaf(rz, pw1[5], pb1[1])));
    float u2 = fmaf(rx, pw1[6], fmaf(ry, pw1[7], fmaf(rz, pw1[8], pb1[2])));
    d0 = fmaxf(fmaf(u0, sspos[0], sspos[4]), 0.f);
    d1 = fmaxf(fmaf(u1, sspos[1], sspos[5]), 0.f);
    d2 = fmaxf(fmaf(u2, sspos[2], sspos[6]), 0.f);
}

// ---------------------------------------------------------------------------
// Stats of u = rel @ pos_w1^T + pos_b1 over E edges (3 channels, pad 4).
__global__ __launch_bounds__(256)
void k_pos_stats(const float* __restrict__ pos, const int* __restrict__ src,
                 const float* __restrict__ pw1, const float* __restrict__ pb1,
                 float* __restrict__ part)
{
    float s0 = 0, s1 = 0, s2 = 0, q0 = 0, q1 = 0, q2 = 0;
    int tid = blockIdx.x * 256 + threadIdx.x;
    for (int e = tid; e < E_; e += 1024 * 256) {
        int si = src[e], di = e >> 4;
        float rx = pos[3 * si + 0] - pos[3 * di + 0];
        float ry = pos[3 * si + 1] - pos[3 * di + 1];
        float rz = pos[3 * si + 2] - pos[3 * di + 2];
        float u0 = fmaf(rx, pw1[0], fmaf(ry, pw1[1], fmaf(rz, pw1[2], pb1[0])));
        float u1 = fmaf(rx, pw1[3], fmaf(ry, pw1[4], fmaf(rz, pw1[5], pb1[1])));
        float u2 = fmaf(rx, pw1[6], fmaf(ry, pw1[7], fmaf(rz, pw1[8], pb1[2])));
        s0 += u0; q0 = fmaf(u0, u0, q0);
        s1 += u1; q1 = fmaf(u1, u1, q1);
        s2 += u2; q2 = fmaf(u2, u2, q2);
    }
#pragma unroll
    for (int m = 1; m < 64; m <<= 1) {
        s0 += __shfl_xor(s0, m, 64); s1 += __shfl_xor(s1, m, 64); s2 += __shfl_xor(s2, m, 64);
        q0 += __shfl_xor(q0, m, 64); q1 += __shfl_xor(q1, m, 64); q2 += __shfl_xor(q2, m, 64);
    }
    __shared__ float red[4][8];
    int wv = threadIdx.x >> 6, ln = threadIdx.x & 63;
    if (ln == 0) {
        red[wv][0] = s0; red[wv][1] = s1; red[wv][2] = s2; red[wv][3] = 0.f;
        red[wv][4] = q0; red[wv][5] = q1; red[wv][6] = q2; red[wv][7] = 0.f;
    }
    __syncthreads();
    if (threadIdx.x < 8)
        part[blockIdx.x * 8 + threadIdx.x] =
            red[0][threadIdx.x] + red[1][threadIdx.x] + red[2][threadIdx.x] + red[3][threadIdx.x];
}

// ---------------------------------------------------------------------------
// Stats of a = a_src[src] - a_dst[dst] + delta over E edges (64 channels).
// One thread per edge; a recomputed, never stored.
__global__ __launch_bounds__(256)
void k_abn1_stats(const float* __restrict__ pos, const int* __restrict__ src,
                  const float* __restrict__ asrc, const float* __restrict__ adst,
                  const float* __restrict__ pw1, const float* __restrict__ pb1,
                  const float* __restrict__ sspos, const float* __restrict__ pw2,
                  const float* __restrict__ pb2, float* __restrict__ part)
{
    float sacc[64], qacc[64];
#pragma unroll
    for (int i = 0; i < 64; ++i) { sacc[i] = 0.f; qacc[i] = 0.f; }
    int tid = blockIdx.x * 256 + threadIdx.x;
    for (int e = tid; e < E_; e += 1024 * 256) {
        int si = src[e], di = e >> 4;
        float d0, d1, d2;
        compute_d(pos, si, di, pw1, pb1, sspos, d0, d1, d2);
        const float4* ar = (const float4*)(asrc + (size_t)si * 64);
        const float4* dr = (const float4*)(adst + (size_t)di * 64);
#pragma unroll
        for (int c4 = 0; c4 < 16; ++c4) {
            float4 av = ar[c4], dv = dr[c4];
            int c = 4 * c4;
#define PROCA(comp, cc) { \
            float del = fmaf(d0, pw2[3*(cc)+0], fmaf(d1, pw2[3*(cc)+1], fmaf(d2, pw2[3*(cc)+2], pb2[(cc)]))); \
            float a = av.comp - dv.comp + del; \
            sacc[(cc)] += a; qacc[(cc)] = fmaf(a, a, qacc[(cc)]); }
            PROCA(x, c + 0) PROCA(y, c + 1) PROCA(z, c + 2) PROCA(w, c + 3)
#undef PROCA
        }
    }
#pragma unroll
    for (int c = 0; c < 64; ++c) {
        float s = sacc[c], q = qacc[c];
#pragma unroll
        for (int m = 1; m < 64; m <<= 1) { s += __shfl_xor(s, m, 64); q += __shfl_xor(q, m, 64); }
        sacc[c] = s; qacc[c] = q;
    }
    __shared__ float red[4][128];
    int wv = threadIdx.x >> 6, ln = threadIdx.x & 63;
    if (ln == 0) {
#pragma unroll
        for (int c = 0; c < 64; ++c) { red[wv][c] = sacc[c]; red[wv][64 + c] = qacc[c]; }
    }
    __syncthreads();
    if (threadIdx.x < 128)
        part[blockIdx.x * 128 + threadIdx.x] =
            red[0][threadIdx.x] + red[1][threadIdx.x] + red[2][threadIdx.x] + red[3][threadIdx.x];
}

// ---------------------------------------------------------------------------
// t1 = relu(abn1(a)) @ attn_w1^T + attn_b1  [E,8]; also abn2 stats (8 ch).
__global__ __launch_bounds__(256)
void k_edge_t1(const float* __restrict__ pos, const int* __restrict__ src,
               const float* __restrict__ asrc, const float* __restrict__ adst,
               const float* __restrict__ pw1, const float* __restrict__ pb1,
               const float* __restrict__ sspos, const float* __restrict__ pw2,
               const float* __restrict__ pb2, const float* __restrict__ ssa1,
               const float* __restrict__ aw1, const float* __restrict__ ab1,
               float* __restrict__ t1, float* __restrict__ part)
{
    float ssum[8], sq[8];
#pragma unroll
    for (int j = 0; j < 8; ++j) { ssum[j] = 0.f; sq[j] = 0.f; }
    int tid = blockIdx.x * 256 + threadIdx.x;
    for (int e = tid; e < E_; e += 1024 * 256) {
        int si = src[e], di = e >> 4;
        float d0, d1, d2;
        compute_d(pos, si, di, pw1, pb1, sspos, d0, d1, d2);
        const float4* ar = (const float4*)(asrc + (size_t)si * 64);
        const float4* dr = (const float4*)(adst + (size_t)di * 64);
        float tp[8];
#pragma unroll
        for (int j = 0; j < 8; ++j) tp[j] = ab1[j];
#pragma unroll
        for (int c4 = 0; c4 < 16; ++c4) {
            float4 av = ar[c4], dv = dr[c4];
            int c = 4 * c4;
#define PROCB(comp, cc) { \
            float del = fmaf(d0, pw2[3*(cc)+0], fmaf(d1, pw2[3*(cc)+1], fmaf(d2, pw2[3*(cc)+2], pb2[(cc)]))); \
            float a = av.comp - dv.comp + del; \
            float an = fmaxf(fmaf(a, ssa1[(cc)], ssa1[64 + (cc)]), 0.f); \
            _Pragma("unroll") \
            for (int j = 0; j < 8; ++j) tp[j] = fmaf(an, aw1[j * 64 + (cc)], tp[j]); }
            PROCB(x, c + 0) PROCB(y, c + 1) PROCB(z, c + 2) PROCB(w, c + 3)
#undef PROCB
        }
        float4 o0 = {tp[0], tp[1], tp[2], tp[3]};
        float4 o1 = {tp[4], tp[5], tp[6], tp[7]};
        float4* t4 = (float4*)(t1 + (size_t)e * 8);
        t4[0] = o0; t4[1] = o1;
#pragma unroll
        for (int j = 0; j < 8; ++j) { ssum[j] += tp[j]; sq[j] = fmaf(tp[j], tp[j], sq[j]); }
    }
#pragma unroll
    for (int j = 0; j < 8; ++j) {
        float s = ssum[j], q = sq[j];
#pragma unroll
        for (int m = 1; m < 64; m <<= 1) { s += __shfl_xor(s, m, 64); q += __shfl_xor(q, m, 64); }
        ssum[j] = s; sq[j] = q;
    }
    __shared__ float red[4][16];
    int wv = threadIdx.x >> 6, ln = threadIdx.x & 63;
    if (ln == 0) {
#pragma unroll
        for (int j = 0; j < 8; ++j) { red[wv][j] = ssum[j]; red[wv][8 + j] = sq[j]; }
    }
    __syncthreads();
    if (threadIdx.x < 16)
        part[blockIdx.x * 16 + threadIdx.x] =
            red[0][threadIdx.x] + red[1][threadIdx.x] + red[2][threadIdx.x] + red[3][threadIdx.x];
}

// ---------------------------------------------------------------------------
// Final edge pass: t2 = relu(abn2(t1)) @ attn_w2^T + attn_b2; softmax over
// each node's 16 contiguous edges (16-lane shfl groups); weighted aggregate
// out[n,c] = sum_k alpha[k][c&7] * (hW[src_k,c] + delta_k[c]).
__global__ __launch_bounds__(256)
void k_node_aggr(const float* __restrict__ pos, const int* __restrict__ src,
                 const float* __restrict__ t1, const float* __restrict__ ssa2,
                 const float* __restrict__ aw2, const float* __restrict__ ab2,
                 const float* __restrict__ hw, const float* __restrict__ sspos,
                 const float* __restrict__ pw1, const float* __restrict__ pb1,
                 const float* __restrict__ pw2, const float* __restrict__ pb2,
                 float* __restrict__ out)
{
    int t = threadIdx.x;
    int e = blockIdx.x * 256 + t;
    int n = e >> 4;
    int k = t & 15;
    const float4* t4 = (const float4*)(t1 + (size_t)e * 8);
    float4 ta = t4[0], tb = t4[1];
    float tv[8] = {ta.x, ta.y, ta.z, ta.w, tb.x, tb.y, tb.z, tb.w};
    float tn[8];
#pragma unroll
    for (int j = 0; j < 8; ++j) tn[j] = fmaxf(fmaf(tv[j], ssa2[j], ssa2[8 + j]), 0.f);
    float al[8];
#pragma unroll
    for (int j = 0; j < 8; ++j) {
        float acc = ab2[j];
#pragma unroll
        for (int i = 0; i < 8; ++i) acc = fmaf(tn[i], aw2[j * 8 + i], acc);
        float m = acc;
#pragma unroll
        for (int msk = 1; msk < 16; msk <<= 1) m = fmaxf(m, __shfl_xor(m, msk, 64));
        float ex = __expf(acc - m);
        float sm = ex;
#pragma unroll
        for (int msk = 1; msk < 16; msk <<= 1) sm += __shfl_xor(sm, msk, 64);
        al[j] = ex / sm;
    }
    int si = src[e];
    float d0, d1, d2;
    compute_d(pos, si, n, pw1, pb1, sspos, d0, d1, d2);
    const float4* hr = (const float4*)(hw + (size_t)si * 64);
    float4 keep = {0.f, 0.f, 0.f, 0.f};
#pragma unroll
    for (int c4 = 0; c4 < 16; ++c4) {
        float4 hv = hr[c4];
        int c = 4 * c4;
        float m0 = (hv.x + fmaf(d0, pw2[3*c+0], fmaf(d1, pw2[3*c+1],  fmaf(d2, pw2[3*c+2],  pb2[c+0])))) * al[(c+0)&7];
        float m1 = (hv.y + fmaf(d0, pw2[3*c+3], fmaf(d1, pw2[3*c+4],  fmaf(d2, pw2[3*c+5],  pb2[c+1])))) * al[(c+1)&7];
        float m2 = (hv.z + fmaf(d0, pw2[3*c+6], fmaf(d1, pw2[3*c+7],  fmaf(d2, pw2[3*c+8],  pb2[c+2])))) * al[(c+2)&7];
        float m3 = (hv.w + fmaf(d0, pw2[3*c+9], fmaf(d1, pw2[3*c+10], fmaf(d2, pw2[3*c+11], pb2[c+3])))) * al[(c+3)&7];
#pragma unroll
        for (int msk = 1; msk < 16; msk <<= 1) {
            m0 += __shfl_xor(m0, msk, 64); m1 += __shfl_xor(m1, msk, 64);
            m2 += __shfl_xor(m2, msk, 64); m3 += __shfl_xor(m3, msk, 64);
        }
        if (k == c4) { keep.x = m0; keep.y = m1; keep.z = m2; keep.w = m3; }
    }
    ((float4*)out)[(size_t)n * 16 + k] = keep;
}

// ---------------------------------------------------------------------------
// out = relu(bn3(y3) + x_skip)
__global__ __launch_bounds__(256)
void k_final(const float* __restrict__ y3, const float* __restrict__ ss3,
             const float* __restrict__ x, float* __restrict__ out)
{
    int i = blockIdx.x * 256 + threadIdx.x;   // float4 index
    int c4 = i & 15;
    float4 sc = ((const float4*)ss3)[c4];
    float4 sh = ((const float4*)(ss3 + 64))[c4];
    float4 v  = ((const float4*)y3)[i];
    float4 xs = ((const float4*)x)[i];
    float4 o;
    o.x = fmaxf(fmaf(v.x, sc.x, sh.x) + xs.x, 0.f);
    o.y = fmaxf(fmaf(v.y, sc.y, sh.y) + xs.y, 0.f);
    o.z = fmaxf(fmaf(v.z, sc.z, sh.z) + xs.z, 0.f);
    o.w = fmaxf(fmaf(v.w, sc.w, sh.w) + xs.w, 0.f);
    ((float4*)out)[i] = o;
}

// ---------------------------------------------------------------------------
extern "C" void kernel_launch(void* const* d_in, const int* in_sizes, int n_in,
                              void* d_out, int out_size, void* d_ws, size_t ws_size,
                              hipStream_t stream)
{
    const float* x    = (const float*)d_in[0];
    const float* pos  = (const float*)d_in[1];
    const int*   src  = (const int*)d_in[2];           // edge_index row 0
    const float* W_in = (const float*)d_in[3];
    const float* W_out= (const float*)d_in[4];
    const float* pw1  = (const float*)d_in[5];
    const float* pb1  = (const float*)d_in[6];
    const float* pbg  = (const float*)d_in[7];
    const float* pbb  = (const float*)d_in[8];
    const float* pw2  = (const float*)d_in[9];
    const float* pb2  = (const float*)d_in[10];
    const float* a1g  = (const float*)d_in[11];
    const float* a1b  = (const float*)d_in[12];
    const float* aw1  = (const float*)d_in[13];
    const float* ab1  = (const float*)d_in[14];
    const float* a2g  = (const float*)d_in[15];
    const float* a2b  = (const float*)d_in[16];
    const float* aw2  = (const float*)d_in[17];
    const float* ab2  = (const float*)d_in[18];
    const float* linw = (const float*)d_in[19];
    const float* linb = (const float*)d_in[20];
    const float* srcw = (const float*)d_in[21];
    const float* srcb = (const float*)d_in[22];
    const float* dstw = (const float*)d_in[23];
    const float* dstb = (const float*)d_in[24];
    const float* bn1g = (const float*)d_in[25];
    const float* bn1b = (const float*)d_in[26];
    const float* bn2g = (const float*)d_in[27];
    const float* bn2b = (const float*)d_in[28];
    const float* bn3g = (const float*)d_in[29];
    const float* bn3b = (const float*)d_in[30];
    float* outp = (float*)d_out;

    float* ws = (float*)d_ws;
    const size_t NC = (size_t)N_ * C_;
    float* buf_y    = ws;                 // y1, later y3
    float* buf_asrc = ws + NC;            // a_src, later reused as `out` aggregate
    float* buf_adst = ws + 2 * NC;
    float* buf_hw   = ws + 3 * NC;
    float* buf_t1   = ws + 4 * NC;        // [E,8]
    float* pbase    = ws + 4 * NC + (size_t)E_ * 8;
    float* p_bn1  = pbase;                 // 256*128
    float* p_pos  = p_bn1  + 256 * 128;    // 1024*8
    float* p_abn1 = p_pos  + 1024 * 8;     // 1024*128
    float* p_abn2 = p_abn1 + 1024 * 128;   // 1024*16
    float* p_bn2  = p_abn2 + 1024 * 16;    // 256*128
    float* p_bn3  = p_bn2  + 256 * 128;    // 256*128
    float* ssb    = p_bn3  + 256 * 128;
    float* ss_bn1 = ssb;         // [scale 64][shift 64]
    float* ss_pos = ssb + 128;   // [scale 4][shift 4]
    float* ss_a1  = ssb + 136;   // 128
    float* ss_a2  = ssb + 264;   // 16
    float* ss_bn2 = ssb + 280;   // 128
    float* ss_bn3 = ssb + 408;   // 128

    float* buf_out = buf_asrc;   // reuse after a_src consumed

    // 1) y1 = x @ W_in^T
    k_gemm_node<<<256, 256, 0, stream>>>(x, W_in, nullptr, nullptr, buf_y);
    // 2-3) bn1 stats
    k_colstats<<<256, 256, 0, stream>>>(buf_y, p_bn1);
    k_reduce_bn<<<1, 1024, 0, stream>>>(p_bn1, 256, 64, 64, 1.f / N_, bn1g, bn1b, ss_bn1);
    // 4) h = relu(bn1(y1)); a_src/a_dst/hW
    k_gemm3<<<256, 256, 0, stream>>>(buf_y, ss_bn1, srcw, srcb, dstw, dstb, linw, linb,
                                     buf_asrc, buf_adst, buf_hw);
    // 5-6) pos-BN stats
    k_pos_stats<<<1024, 256, 0, stream>>>(pos, src, pw1, pb1, p_pos);
    k_reduce_bn<<<1, 1024, 0, stream>>>(p_pos, 1024, 4, 3, 1.f / E_, pbg, pbb, ss_pos);
    // 7-8) attn_bn1 stats (a recomputed on the fly)
    k_abn1_stats<<<1024, 256, 0, stream>>>(pos, src, buf_asrc, buf_adst,
                                           pw1, pb1, ss_pos, pw2, pb2, p_abn1);
    k_reduce_bn<<<1, 1024, 0, stream>>>(p_abn1, 1024, 64, 64, 1.f / E_, a1g, a1b, ss_a1);
    // 9-10) t1 = relu(abn1(a)) @ attn_w1^T + b1 ; abn2 stats
    k_edge_t1<<<1024, 256, 0, stream>>>(pos, src, buf_asrc, buf_adst,
                                        pw1, pb1, ss_pos, pw2, pb2,
                                        ss_a1, aw1, ab1, buf_t1, p_abn2);
    k_reduce_bn<<<1, 1024, 0, stream>>>(p_abn2, 1024, 8, 8, 1.f / E_, a2g, a2b, ss_a2);
    // 11) softmax + weighted aggregate -> out [N,64]
    k_node_aggr<<<E_ / 256, 256, 0, stream>>>(pos, src, buf_t1, ss_a2, aw2, ab2,
                                              buf_hw, ss_pos, pw1, pb1, pw2, pb2, buf_out);
    // 12-13) bn2 stats
    k_colstats<<<256, 256, 0, stream>>>(buf_out, p_bn2);
    k_reduce_bn<<<1, 1024, 0, stream>>>(p_bn2, 256, 64, 64, 1.f / N_, bn2g, bn2b, ss_bn2);
    // 14) y3 = relu(bn2(out)) @ W_out^T
    k_gemm_node<<<256, 256, 0, stream>>>(buf_out, W_out, nullptr, ss_bn2, buf_y);
    // 15-16) bn3 stats
    k_colstats<<<256, 256, 0, stream>>>(buf_y, p_bn3);
    k_reduce_bn<<<1, 1024, 0, stream>>>(p_bn3, 256, 64, 64, 1.f / N_, bn3g, bn3b, ss_bn3);
    // 17) out = relu(bn3(y3) + x)
    k_final<<<(N_ * C_ / 4) / 256, 256, 0, stream>>>(buf_y, ss_bn3, x, outp);

    (void)in_sizes; (void)n_in; (void)out_size; (void)ws_size;
}